// Round 3
// baseline (829.961 us; speedup 1.0000x reference)
//
#include <hip/hip_runtime.h>
#include <cstddef>
#include <cstdint>

// Problem dims (fixed by reference setup_inputs)
#define N_PATCH 100000
#define D_IN    1024
#define A_DIM   128
#define H_DIM   256
#define KTOP    16

// d_out layout (fp32 flat, reference return order)
#define OUT_LOGIT 0
#define OUT_EMB   1
#define OUT_FW    (1 + D_IN)             // 1025
#define OUT_TOPI  (OUT_FW + N_PATCH)     // 101025

// workspace layout (float units)
#define WS_SCORES 0
#define WS_CANDV  (N_PATCH)                  // 100000
#define WS_CANDI  (N_PATCH + 4096)
#define WS_EMB    (N_PATCH + 2 * 4096)       // 108192
#define WS_HPART  (WS_EMB + D_IN)            // 109216 (16*256 floats)
#define WS_WPK    (WS_HPART + 16 * H_DIM)    // 113312, 16B-aligned (x4 bytes)

// stage-2a config
#define NB2A  256
#define CHUNK 391   // ceil(100000/256)

typedef __attribute__((ext_vector_type(8))) short bf8_t;   // 8 bf16 (4 VGPRs)
typedef __attribute__((ext_vector_type(4))) float f4_t;    // MFMA C/D frag

// ---------------- Stage 0: prepack Wa1 -> bf16 (RNE) in B-fragment layout ----
// chunk t in [0, 16384): lane=t&63, nt=(t>>6)&7, ks=t>>9
// chunk holds 8 bf16: element j -> W[k = ks*32 + (lane>>4)*8 + j][n = nt*16 + (lane&15)]
__global__ __launch_bounds__(256) void k_prepack(
    const float* __restrict__ Wa1, uint4* __restrict__ wpk)
{
    int t = blockIdx.x * 256 + threadIdx.x;     // grid 64 blocks -> 16384 chunks
    int lane = t & 63;
    int nt   = (t >> 6) & 7;
    int ks   = t >> 9;
    int n  = nt * 16 + (lane & 15);
    int k0 = ks * 32 + ((lane >> 4) * 8);
    union { ushort u[8]; uint4 v; } o;
    #pragma unroll
    for (int j = 0; j < 8; ++j) {
        uint b = __float_as_uint(Wa1[(size_t)(k0 + j) * A_DIM + n]);
        // round-to-nearest-even bf16 (bias-free, unlike truncation)
        o.u[j] = (ushort)((b + 0x7fffu + ((b >> 16) & 1u)) >> 16);
    }
    wpk[t] = o.v;
}

// ---------------- Stage 1: scores = tanh(x@Wa1+ba1)@Wa2 + ba2 (bf16 MFMA) ----
// Block: 256 thr = 4 waves; wave covers 32 rows x 128 cols; block = 128 rows.
// Single-term bf16 (RNE both sides): score err ~2e-3 << top-16 margin ~0.05.
// Selected rows are exactly rescored in k_finalize, so output precision does
// not depend on this path. Per-block k-rotation spreads HBM channel traffic.
__device__ __forceinline__ void cvt8(const float4& a, const float4& b, bf8_t& out)
{
    union { uint u[4]; bf8_t v; } O;
    asm("v_cvt_pk_bf16_f32 %0, %1, %2" : "=v"(O.u[0]) : "v"(a.x), "v"(a.y));
    asm("v_cvt_pk_bf16_f32 %0, %1, %2" : "=v"(O.u[1]) : "v"(a.z), "v"(a.w));
    asm("v_cvt_pk_bf16_f32 %0, %1, %2" : "=v"(O.u[2]) : "v"(b.x), "v"(b.y));
    asm("v_cvt_pk_bf16_f32 %0, %1, %2" : "=v"(O.u[3]) : "v"(b.z), "v"(b.w));
    out = O.v;
}

#define MFMA_BF16 __builtin_amdgcn_mfma_f32_16x16x32_bf16

// LDS-visibility barrier that does NOT drain vmcnt: global prefetch loads
// stay in flight across step boundaries.
#define BAR_LDS() do {                                          \
    asm volatile("s_waitcnt lgkmcnt(0)" ::: "memory");          \
    __builtin_amdgcn_s_barrier();                               \
    asm volatile("" ::: "memory");                              \
} while (0)

// One k-step (= half an LDS tile). IT = iter index (runtime), PAR/CUR literal.
// Even half: commit staged B tile (IT+1) to LDS, prefetch B tile (IT+2).
// Every half: prefetch A for the same half of iter IT+1 (depth ~1 iter in flight).
// Odd half: barrier (one barrier per 2 k-steps).
#define SCORE_STEP(IT, PAR, CUR) do {                                          \
    bf8_t ah0, ah1;                                                            \
    cvt8(A##CUR[0], A##CUR[1], ah0);                                           \
    cvt8(A##CUR[2], A##CUR[3], ah1);                                           \
    if ((PAR) == 0) {                                                          \
        _Pragma("unroll")                                                      \
        for (int i = 0; i < 4; ++i) sB[bufp ^ 1][tid + i * 256] = bpre[i];     \
        const int vtp = (t0 + (IT) + 2) & 15;                                  \
        _Pragma("unroll")                                                      \
        for (int i = 0; i < 4; ++i) bpre[i] = wpk[vtp * 1024 + tid + i * 256]; \
    }                                                                          \
    {                                                                          \
        const int kg2 = (((t0 + (IT) + 1) & 15) * 2 + (PAR)) * 32;             \
        A##CUR[0] = *(const float4*)(pa0 + kg2);                               \
        A##CUR[1] = *(const float4*)(pa0 + kg2 + 4);                           \
        A##CUR[2] = *(const float4*)(pa1 + kg2);                               \
        A##CUR[3] = *(const float4*)(pa1 + kg2 + 4);                           \
    }                                                                          \
    const bf8_t* sBf = (const bf8_t*)sB[bufp] + (PAR) * 512;                   \
    _Pragma("unroll")                                                          \
    for (int nt = 0; nt < 8; nt += 2) {                                        \
        bf8_t b0 = sBf[nt * 64 + ln];                                          \
        bf8_t b1 = sBf[(nt + 1) * 64 + ln];                                    \
        acc[0][nt]     = MFMA_BF16(ah0, b0, acc[0][nt],     0, 0, 0);          \
        acc[1][nt]     = MFMA_BF16(ah1, b0, acc[1][nt],     0, 0, 0);          \
        acc[0][nt + 1] = MFMA_BF16(ah0, b1, acc[0][nt + 1], 0, 0, 0);          \
        acc[1][nt + 1] = MFMA_BF16(ah1, b1, acc[1][nt + 1], 0, 0, 0);          \
    }                                                                          \
    if (PAR) BAR_LDS();                                                        \
} while (0)

__global__ __launch_bounds__(256) void k_scores(
    const float* __restrict__ x, const uint4* __restrict__ wpk,
    const float* __restrict__ ba1, const float* __restrict__ Wa2,
    const float* __restrict__ ba2, float* __restrict__ scores)
{
    __shared__ uint4 sB[2][1024];   // 32 KB double buffer; 1 tile = 2 k-steps

    const int tid = threadIdx.x;
    const int ln  = tid & 63;
    const int q   = ln >> 4;      // k-quad
    const int c   = ln & 15;      // col selector (B) / row selector (A)
    const int wv  = tid >> 6;
    const int row0 = blockIdx.x * 128 + wv * 32;
    const int t0   = blockIdx.x & 15;   // per-block tile rotation (16 tiles)

    // A-stream pointers (fragment layout: row = c, k = q*8 + j)
    const int r0 = min(row0 + c,      N_PATCH - 1);
    const int r1 = min(row0 + 16 + c, N_PATCH - 1);
    const float* pa0 = x + (size_t)r0 * D_IN + q * 8;
    const float* pa1 = x + (size_t)r1 * D_IN + q * 8;

    f4_t acc[2][8];
    #pragma unroll
    for (int rt = 0; rt < 2; ++rt)
        #pragma unroll
        for (int nt = 0; nt < 8; ++nt)
            acc[rt][nt] = (f4_t){0.f, 0.f, 0.f, 0.f};

    // ---- prologue: stage tile t0 into LDS, prefetch tile t0+1, A halves 0+1 -
    uint4 bpre[4];
    {
        uint4 b0[4];
        #pragma unroll
        for (int i = 0; i < 4; ++i) b0[i] = wpk[t0 * 1024 + tid + i * 256];
        #pragma unroll
        for (int i = 0; i < 4; ++i) sB[0][tid + i * 256] = b0[i];
    }
    {
        const int t1 = (t0 + 1) & 15;
        #pragma unroll
        for (int i = 0; i < 4; ++i) bpre[i] = wpk[t1 * 1024 + tid + i * 256];
    }

    float4 A0[4], A1[4];          // per-half A buffers, statically indexed
    {
        const int ka = (t0 * 2) * 32;
        const int kb = (t0 * 2 + 1) * 32;
        A0[0] = *(const float4*)(pa0 + ka);
        A0[1] = *(const float4*)(pa0 + ka + 4);
        A0[2] = *(const float4*)(pa1 + ka);
        A0[3] = *(const float4*)(pa1 + ka + 4);
        A1[0] = *(const float4*)(pa0 + kb);
        A1[1] = *(const float4*)(pa0 + kb + 4);
        A1[2] = *(const float4*)(pa1 + kb);
        A1[3] = *(const float4*)(pa1 + kb + 4);
    }

    BAR_LDS();

    for (int it = 0; it < 16; ++it) {
        const int bufp = it & 1;
        SCORE_STEP(it, 0, 0);
        SCORE_STEP(it, 1, 1);
    }

    // epilogue: +ba1, tanh, dot Wa2, reduce over the 16 lanes sharing rows
    float b1v[8], w2v[8];
    #pragma unroll
    for (int nt = 0; nt < 8; ++nt) {
        b1v[nt] = ba1[nt * 16 + c];
        w2v[nt] = Wa2[nt * 16 + c];
    }
    const float b2 = ba2[0];

    #pragma unroll
    for (int rt = 0; rt < 2; ++rt)
        #pragma unroll
        for (int reg = 0; reg < 4; ++reg) {
            float p = 0.f;
            #pragma unroll
            for (int nt = 0; nt < 8; ++nt)
                p += tanhf(acc[rt][nt][reg] + b1v[nt]) * w2v[nt];
            #pragma unroll
            for (int off = 1; off < 16; off <<= 1)
                p += __shfl_xor(p, off, 64);
            if (c == 0) {
                int row = row0 + rt * 16 + q * 4 + reg;   // C/D: row = quad*4+reg
                if (row < N_PATCH) scores[row] = p + b2;
            }
        }
}

// ---------------- Stage 2a: per-block local top-16 + zero full_weights -------
__global__ __launch_bounds__(256) void k_topk_local(
    const float* __restrict__ scores, float* __restrict__ candv,
    int* __restrict__ candi, float* __restrict__ out_fw)
{
    __shared__ float sv[512];
    __shared__ float rv[256];
    __shared__ int   rs[256];
    const int tid  = threadIdx.x;
    const int base = blockIdx.x * CHUNK;

    for (int i = tid; i < 512; i += 256) {
        int g = base + i;
        sv[i] = (i < CHUNK && g < N_PATCH) ? scores[g] : -1e30f;
    }
    for (int i = tid; i < CHUNK; i += 256) {
        int g = base + i;
        if (g < N_PATCH) out_fw[g] = 0.f;   // zero full_weights (d_out is poisoned)
    }
    __syncthreads();

    for (int r = 0; r < KTOP; ++r) {
        float v1 = sv[tid], v2 = sv[tid + 256];
        float bv; int bs;
        if (v2 > v1) { bv = v2; bs = tid + 256; } else { bv = v1; bs = tid; }
        rv[tid] = bv; rs[tid] = bs;
        __syncthreads();
        for (int off = 128; off > 0; off >>= 1) {
            if (tid < off) {
                float ov = rv[tid + off]; int os = rs[tid + off];
                if (ov > rv[tid] || (ov == rv[tid] && os < rs[tid])) {
                    rv[tid] = ov; rs[tid] = os;
                }
            }
            __syncthreads();
        }
        if (tid == 0) {
            int s = rs[0];
            candv[blockIdx.x * KTOP + r] = rv[0];
            candi[blockIdx.x * KTOP + r] = base + s;
            sv[s] = -1e30f;
        }
        __syncthreads();
    }
}

// ---------------- Stage 2b: global top-16 (approx select), EXACT fp32 rescore,
//                  sort, softmax, scatter, embedding (single block) -----------
__global__ __launch_bounds__(256) void k_finalize(
    const float* __restrict__ candv, const int* __restrict__ candi,
    const float* __restrict__ x, const float* __restrict__ Wa1,
    const float* __restrict__ ba1, const float* __restrict__ Wa2,
    const float* __restrict__ ba2, float* __restrict__ out,
    float* __restrict__ emb)
{
    __shared__ float cv[4096];
    __shared__ int   ci[4096];
    __shared__ float rv[256];
    __shared__ int   rgx[256];
    __shared__ int   rsl[256];
    __shared__ int   topi[KTOP];
    __shared__ float sxs[KTOP][D_IN] __attribute__((aligned(16)));  // 64 KB
    __shared__ float sred[KTOP][128];                               // 8 KB
    __shared__ float exv[KTOP];
    __shared__ float attn[KTOP];
    __shared__ int   order[KTOP];
    const int tid = threadIdx.x;

    for (int i = tid; i < 4096; i += 256) { cv[i] = candv[i]; ci[i] = candi[i]; }
    __syncthreads();

    // merge 4096 candidates -> top-16 set (by approximate scores; margin >> err)
    for (int r = 0; r < KTOP; ++r) {
        float bv = -1e38f; int bg = 0x7fffffff; int bs = tid * 16;
        #pragma unroll
        for (int i = 0; i < 16; ++i) {
            int s = tid * 16 + i;
            float v = cv[s]; int g = ci[s];
            if (v > bv || (v == bv && g < bg)) { bv = v; bg = g; bs = s; }
        }
        rv[tid] = bv; rgx[tid] = bg; rsl[tid] = bs;
        __syncthreads();
        for (int off = 128; off > 0; off >>= 1) {
            if (tid < off) {
                if (rv[tid + off] > rv[tid] ||
                    (rv[tid + off] == rv[tid] && rgx[tid + off] < rgx[tid])) {
                    rv[tid] = rv[tid + off]; rgx[tid] = rgx[tid + off]; rsl[tid] = rsl[tid + off];
                }
            }
            __syncthreads();
        }
        if (tid == 0) {
            topi[r] = rgx[0]; cv[rsl[0]] = -1e30f;
        }
        __syncthreads();
    }

    // stage the 16 selected rows of x into LDS (reused by rescore + embedding)
    for (int r = 0; r < KTOP; ++r)
        for (int d = tid; d < D_IN; d += 256)
            sxs[r][d] = x[(size_t)topi[r] * D_IN + d];
    __syncthreads();

    // EXACT fp32 rescore: scores[r] = tanh(x_r @ Wa1 + ba1) @ Wa2 + ba2.
    // 256 thr = 2 groups x 128 cols; each thread: 8 rows x 1024 fp32 FMAs.
    {
        const int g = tid >> 7, n = tid & 127;
        float ac[8];
        #pragma unroll
        for (int rr = 0; rr < 8; ++rr) ac[rr] = 0.f;
        #pragma unroll 4
        for (int d = 0; d < D_IN; ++d) {
            const float w = Wa1[(size_t)d * A_DIM + n];
            #pragma unroll
            for (int rr = 0; rr < 8; ++rr)
                ac[rr] = fmaf(sxs[g * 8 + rr][d], w, ac[rr]);
        }
        const float bn = ba1[n], wn = Wa2[n];
        #pragma unroll
        for (int rr = 0; rr < 8; ++rr)
            sred[g * 8 + rr][n] = tanhf(ac[rr] + bn) * wn;
    }
    __syncthreads();
    if (tid < KTOP) {
        float s = ba2[0];
        for (int n = 0; n < 128; ++n) s += sred[tid][n];
        exv[tid] = s;
    }
    __syncthreads();

    // sort by (exact value desc, index asc) to match lax.top_k output order
    if (tid == 0) {
        #pragma unroll
        for (int k2 = 0; k2 < KTOP; ++k2) order[k2] = k2;
        for (int a2 = 1; a2 < KTOP; ++a2)
            for (int b2 = a2; b2 > 0; --b2) {
                int i1 = order[b2 - 1], i2 = order[b2];
                bool sw = (exv[i2] > exv[i1]) ||
                          (exv[i2] == exv[i1] && topi[i2] < topi[i1]);
                if (sw) { order[b2 - 1] = i2; order[b2] = i1; } else break;
            }
        float mx = exv[order[0]];
        float ssum = 0.f;
        for (int k2 = 0; k2 < KTOP; ++k2) {
            float e = expf(exv[order[k2]] - mx);
            attn[k2] = e; ssum += e;
        }
        float inv = 1.f / ssum;
        for (int k2 = 0; k2 < KTOP; ++k2) attn[k2] *= inv;
    }
    __syncthreads();

    if (tid < KTOP) {
        int src = order[tid];
        out[OUT_TOPI + tid] = (float)topi[src];
        out[OUT_FW + topi[src]] = attn[tid];
    }

    // ---- embedding: 4 dims per thread, rows already in LDS ------------------
    float4 e = {0.f, 0.f, 0.f, 0.f};
    #pragma unroll
    for (int k2 = 0; k2 < KTOP; ++k2) {
        const int src = order[k2];
        const float a = attn[k2];
        const float4 xv = *(const float4*)(&sxs[src][tid * 4]);
        e.x = fmaf(a, xv.x, e.x);
        e.y = fmaf(a, xv.y, e.y);
        e.z = fmaf(a, xv.z, e.z);
        e.w = fmaf(a, xv.w, e.w);
    }
    out[OUT_EMB + tid * 4 + 0] = e.x;   // OUT_EMB offset is odd -> scalar stores
    out[OUT_EMB + tid * 4 + 1] = e.y;
    out[OUT_EMB + tid * 4 + 2] = e.z;
    out[OUT_EMB + tid * 4 + 3] = e.w;
    *(float4*)(emb + tid * 4) = e;
}

// ---------------- Stage 4a: h partial sums (16 blocks over d-slices) ---------
__global__ __launch_bounds__(256) void k_mlp1(
    const float* __restrict__ emb, const float* __restrict__ Wc1,
    float* __restrict__ hpart)
{
    __shared__ float se[64];
    const int b = blockIdx.x, tid = threadIdx.x;
    if (tid < 64) se[tid] = emb[b * 64 + tid];
    __syncthreads();
    float p = 0.f;
    #pragma unroll 8
    for (int d = 0; d < 64; ++d)
        p = fmaf(se[d], Wc1[(size_t)(b * 64 + d) * H_DIM + tid], p);
    hpart[b * H_DIM + tid] = p;
}

// ---------------- Stage 4b: relu + Wc2 dot + bias ----------------------------
__global__ __launch_bounds__(256) void k_logit(
    const float* __restrict__ hpart, const float* __restrict__ bc1,
    const float* __restrict__ Wc2, const float* __restrict__ bc2,
    float* __restrict__ out)
{
    __shared__ float red[256];
    const int tid = threadIdx.x;
    float h = bc1[tid];
    #pragma unroll
    for (int i = 0; i < 16; ++i) h += hpart[i * H_DIM + tid];
    h = fmaxf(h, 0.f) * Wc2[tid];
    red[tid] = h;
    __syncthreads();
    for (int off = 128; off > 0; off >>= 1) {
        if (tid < off) red[tid] += red[tid + off];
        __syncthreads();
    }
    if (tid == 0) out[OUT_LOGIT] = red[0] + bc2[0];
}

// ---------------- Launch ------------------------------------------------------
extern "C" void kernel_launch(void* const* d_in, const int* in_sizes, int n_in,
                              void* d_out, int out_size, void* d_ws, size_t ws_size,
                              hipStream_t stream)
{
    const float* x   = (const float*)d_in[0];
    const float* Wa1 = (const float*)d_in[1];
    const float* ba1 = (const float*)d_in[2];
    const float* Wa2 = (const float*)d_in[3];
    const float* ba2 = (const float*)d_in[4];
    const float* Wc1 = (const float*)d_in[5];
    const float* bc1 = (const float*)d_in[6];
    const float* Wc2 = (const float*)d_in[7];
    const float* bc2 = (const float*)d_in[8];
    float* out = (float*)d_out;
    float* ws  = (float*)d_ws;

    float* scores = ws + WS_SCORES;
    float* candv  = ws + WS_CANDV;
    int*   candi  = (int*)(ws + WS_CANDI);
    float* emb    = ws + WS_EMB;
    float* hpart  = ws + WS_HPART;
    uint4* wpk    = (uint4*)(ws + WS_WPK);

    dim3 blk(256);
    k_prepack<<<64, blk, 0, stream>>>(Wa1, wpk);
    k_scores<<<(N_PATCH + 127) / 128, blk, 0, stream>>>(x, wpk, ba1, Wa2, ba2, scores);
    k_topk_local<<<NB2A, blk, 0, stream>>>(scores, candv, candi, out + OUT_FW);
    k_finalize<<<1, blk, 0, stream>>>(candv, candi, x, Wa1, ba1, Wa2, ba2, out, emb);
    k_mlp1<<<16, blk, 0, stream>>>(emb, Wc1, hpart);
    k_logit<<<1, blk, 0, stream>>>(hpart, bc1, Wc2, bc2, out);
}

// Round 4
// 704.265 us; speedup vs baseline: 1.1785x; 1.1785x over previous
//
#include <hip/hip_runtime.h>
#include <cstddef>
#include <cstdint>

// Problem dims (fixed by reference setup_inputs)
#define N_PATCH 100000
#define D_IN    1024
#define A_DIM   128
#define H_DIM   256
#define KTOP    16

// d_out layout (fp32 flat, reference return order)
#define OUT_LOGIT 0
#define OUT_EMB   1
#define OUT_FW    (1 + D_IN)             // 1025
#define OUT_TOPI  (OUT_FW + N_PATCH)     // 101025

// workspace layout (float units)
#define WS_SCORES 0
#define WS_CANDV  (N_PATCH)                  // 100000
#define WS_CANDI  (N_PATCH + 4096)           // 104096
#define WS_TOPI   (N_PATCH + 2 * 4096)       // 108192 (16 ints)
#define WS_EMB    (WS_TOPI + 16)             // 108208
#define WS_HPART  (WS_EMB + D_IN)            // 109232 (16*256 floats)
#define WS_HP2    (WS_HPART + 16 * H_DIM)    // 113328 (16*16*128 floats)
#define WS_WPK    (WS_HP2 + 16 * KTOP * 128) // 146096, 16B-aligned (x4 bytes)

// stage-2a config
#define NB2A  256
#define CHUNK 391   // ceil(100000/256)

typedef __attribute__((ext_vector_type(8))) short bf8_t;   // 8 bf16 (4 VGPRs)
typedef __attribute__((ext_vector_type(4))) float f4_t;    // MFMA C/D frag

// ---------------- Stage 0: prepack Wa1 -> bf16 (RNE) in B-fragment layout ----
// chunk t in [0, 16384): lane=t&63, nt=(t>>6)&7, ks=t>>9
// chunk holds 8 bf16: element j -> W[k = ks*32 + (lane>>4)*8 + j][n = nt*16 + (lane&15)]
__global__ __launch_bounds__(256) void k_prepack(
    const float* __restrict__ Wa1, uint4* __restrict__ wpk)
{
    int t = blockIdx.x * 256 + threadIdx.x;     // grid 64 blocks -> 16384 chunks
    int lane = t & 63;
    int nt   = (t >> 6) & 7;
    int ks   = t >> 9;
    int n  = nt * 16 + (lane & 15);
    int k0 = ks * 32 + ((lane >> 4) * 8);
    union { ushort u[8]; uint4 v; } o;
    #pragma unroll
    for (int j = 0; j < 8; ++j) {
        uint b = __float_as_uint(Wa1[(size_t)(k0 + j) * A_DIM + n]);
        // round-to-nearest-even bf16 (bias-free, unlike truncation)
        o.u[j] = (ushort)((b + 0x7fffu + ((b >> 16) & 1u)) >> 16);
    }
    wpk[t] = o.v;
}

// ---------------- Stage 1: scores = tanh(x@Wa1+ba1)@Wa2 + ba2 (bf16 MFMA) ----
// Block: 256 thr = 4 waves; wave covers 32 rows x 128 cols; block = 128 rows.
// Single-term bf16 (RNE both sides): selection-safe; selected rows get an
// exact fp32 rescore downstream. Per-block tile rotation spreads HBM channels.
// A prefetch depth = 2 iterations (4 statically-named buffer sets).
__device__ __forceinline__ void cvt8(const float4& a, const float4& b, bf8_t& out)
{
    union { uint u[4]; bf8_t v; } O;
    asm("v_cvt_pk_bf16_f32 %0, %1, %2" : "=v"(O.u[0]) : "v"(a.x), "v"(a.y));
    asm("v_cvt_pk_bf16_f32 %0, %1, %2" : "=v"(O.u[1]) : "v"(a.z), "v"(a.w));
    asm("v_cvt_pk_bf16_f32 %0, %1, %2" : "=v"(O.u[2]) : "v"(b.x), "v"(b.y));
    asm("v_cvt_pk_bf16_f32 %0, %1, %2" : "=v"(O.u[3]) : "v"(b.z), "v"(b.w));
    out = O.v;
}

#define MFMA_BF16 __builtin_amdgcn_mfma_f32_16x16x32_bf16

// LDS-visibility barrier that does NOT drain vmcnt: global prefetch loads
// stay in flight across step boundaries.
#define BAR_LDS() do {                                          \
    asm volatile("s_waitcnt lgkmcnt(0)" ::: "memory");          \
    __builtin_amdgcn_s_barrier();                               \
    asm volatile("" ::: "memory");                              \
} while (0)

// Load A half PAR of iteration IT into buffer set BUF (all literals).
#define LOADA(BUF, IT, PAR) do {                                               \
    const int kg = (((t0 + (IT)) & 15) * 2 + (PAR)) * 32;                      \
    A##BUF[0] = *(const float4*)(pa0 + kg);                                    \
    A##BUF[1] = *(const float4*)(pa0 + kg + 4);                                \
    A##BUF[2] = *(const float4*)(pa1 + kg);                                    \
    A##BUF[3] = *(const float4*)(pa1 + kg + 4);                                \
} while (0)

// One k-step (= half an LDS tile). IT iter index, PAR half, BUF A-buffer set,
// BUFP LDS buffer parity — ALL compile-time literals.
// PAR==0: commit staged B tile (it+1) to LDS, prefetch B tile (it+2).
// Every step: reload this A buffer with the same half of iteration IT+2.
// PAR==1: barrier (one barrier per iteration).
#define SCORE_STEP(IT, PAR, BUF, BUFP) do {                                    \
    bf8_t ah0, ah1;                                                            \
    cvt8(A##BUF[0], A##BUF[1], ah0);                                           \
    cvt8(A##BUF[2], A##BUF[3], ah1);                                           \
    if ((PAR) == 0) {                                                          \
        _Pragma("unroll")                                                      \
        for (int i = 0; i < 4; ++i) sB[(BUFP) ^ 1][tid + i * 256] = bpre[i];   \
        const int vtp = (t0 + (IT) + 2) & 15;                                  \
        _Pragma("unroll")                                                      \
        for (int i = 0; i < 4; ++i) bpre[i] = wpk[vtp * 1024 + tid + i * 256]; \
    }                                                                          \
    LOADA(BUF, (IT) + 2, PAR);                                                 \
    const bf8_t* sBf = (const bf8_t*)sB[BUFP] + (PAR) * 512;                   \
    _Pragma("unroll")                                                          \
    for (int nt = 0; nt < 8; nt += 2) {                                        \
        bf8_t b0 = sBf[nt * 64 + ln];                                          \
        bf8_t b1 = sBf[(nt + 1) * 64 + ln];                                    \
        acc[0][nt]     = MFMA_BF16(ah0, b0, acc[0][nt],     0, 0, 0);          \
        acc[1][nt]     = MFMA_BF16(ah1, b0, acc[1][nt],     0, 0, 0);          \
        acc[0][nt + 1] = MFMA_BF16(ah0, b1, acc[0][nt + 1], 0, 0, 0);          \
        acc[1][nt + 1] = MFMA_BF16(ah1, b1, acc[1][nt + 1], 0, 0, 0);          \
    }                                                                          \
    if (PAR) BAR_LDS();                                                        \
} while (0)

__global__ __launch_bounds__(256) void k_scores(
    const float* __restrict__ x, const uint4* __restrict__ wpk,
    const float* __restrict__ ba1, const float* __restrict__ Wa2,
    const float* __restrict__ ba2, float* __restrict__ scores)
{
    __shared__ uint4 sB[2][1024];   // 32 KB double buffer; 1 tile = 2 k-steps

    const int tid = threadIdx.x;
    const int ln  = tid & 63;
    const int q   = ln >> 4;      // k-quad
    const int c   = ln & 15;      // col selector (B) / row selector (A)
    const int wv  = tid >> 6;
    const int row0 = blockIdx.x * 128 + wv * 32;
    const int t0   = blockIdx.x & 15;   // per-block tile rotation (16 tiles)

    // A-stream pointers (fragment layout: row = c, k = q*8 + j)
    const int r0 = min(row0 + c,      N_PATCH - 1);
    const int r1 = min(row0 + 16 + c, N_PATCH - 1);
    const float* pa0 = x + (size_t)r0 * D_IN + q * 8;
    const float* pa1 = x + (size_t)r1 * D_IN + q * 8;

    f4_t acc[2][8];
    #pragma unroll
    for (int rt = 0; rt < 2; ++rt)
        #pragma unroll
        for (int nt = 0; nt < 8; ++nt)
            acc[rt][nt] = (f4_t){0.f, 0.f, 0.f, 0.f};

    // ---- prologue: stage tile t0 into LDS, prefetch tile t0+1, A iters 0+1 --
    uint4 bpre[4];
    {
        uint4 b0[4];
        #pragma unroll
        for (int i = 0; i < 4; ++i) b0[i] = wpk[t0 * 1024 + tid + i * 256];
        #pragma unroll
        for (int i = 0; i < 4; ++i) sB[0][tid + i * 256] = b0[i];
    }
    {
        const int t1 = (t0 + 1) & 15;
        #pragma unroll
        for (int i = 0; i < 4; ++i) bpre[i] = wpk[t1 * 1024 + tid + i * 256];
    }

    float4 AE0[4], AE1[4], AO0[4], AO1[4];   // even/odd iter x half, static
    LOADA(E0, 0, 0);
    LOADA(E1, 0, 1);
    LOADA(O0, 1, 0);
    LOADA(O1, 1, 1);

    BAR_LDS();

    for (int it = 0; it < 16; it += 2) {
        SCORE_STEP(it,     0, E0, 0);
        SCORE_STEP(it,     1, E1, 0);
        SCORE_STEP(it + 1, 0, O0, 1);
        SCORE_STEP(it + 1, 1, O1, 1);
    }

    // epilogue: +ba1, tanh, dot Wa2, reduce over the 16 lanes sharing rows
    float b1v[8], w2v[8];
    #pragma unroll
    for (int nt = 0; nt < 8; ++nt) {
        b1v[nt] = ba1[nt * 16 + c];
        w2v[nt] = Wa2[nt * 16 + c];
    }
    const float b2 = ba2[0];

    #pragma unroll
    for (int rt = 0; rt < 2; ++rt)
        #pragma unroll
        for (int reg = 0; reg < 4; ++reg) {
            float p = 0.f;
            #pragma unroll
            for (int nt = 0; nt < 8; ++nt)
                p += tanhf(acc[rt][nt][reg] + b1v[nt]) * w2v[nt];
            #pragma unroll
            for (int off = 1; off < 16; off <<= 1)
                p += __shfl_xor(p, off, 64);
            if (c == 0) {
                int row = row0 + rt * 16 + q * 4 + reg;   // C/D: row = quad*4+reg
                if (row < N_PATCH) scores[row] = p + b2;
            }
        }
}

// ---------------- Stage 2a: per-block local top-16 + zero full_weights -------
__global__ __launch_bounds__(256) void k_topk_local(
    const float* __restrict__ scores, float* __restrict__ candv,
    int* __restrict__ candi, float* __restrict__ out_fw)
{
    __shared__ float sv[512];
    __shared__ float rv[256];
    __shared__ int   rs[256];
    const int tid  = threadIdx.x;
    const int base = blockIdx.x * CHUNK;

    for (int i = tid; i < 512; i += 256) {
        int g = base + i;
        sv[i] = (i < CHUNK && g < N_PATCH) ? scores[g] : -1e30f;
    }
    for (int i = tid; i < CHUNK; i += 256) {
        int g = base + i;
        if (g < N_PATCH) out_fw[g] = 0.f;   // zero full_weights (d_out is poisoned)
    }
    __syncthreads();

    for (int r = 0; r < KTOP; ++r) {
        float v1 = sv[tid], v2 = sv[tid + 256];
        float bv; int bs;
        if (v2 > v1) { bv = v2; bs = tid + 256; } else { bv = v1; bs = tid; }
        rv[tid] = bv; rs[tid] = bs;
        __syncthreads();
        for (int off = 128; off > 0; off >>= 1) {
            if (tid < off) {
                float ov = rv[tid + off]; int os = rs[tid + off];
                if (ov > rv[tid] || (ov == rv[tid] && os < rs[tid])) {
                    rv[tid] = ov; rs[tid] = os;
                }
            }
            __syncthreads();
        }
        if (tid == 0) {
            int s = rs[0];
            candv[blockIdx.x * KTOP + r] = rv[0];
            candi[blockIdx.x * KTOP + r] = base + s;
            sv[s] = -1e30f;
        }
        __syncthreads();
    }
}

// ---------------- Stage 2b: global top-16 SET selection (approx scores) ------
__global__ __launch_bounds__(256) void k_select(
    const float* __restrict__ candv, const int* __restrict__ candi,
    int* __restrict__ topi_ws)
{
    __shared__ float cv[4096];
    __shared__ int   ci[4096];
    __shared__ float rv[256];
    __shared__ int   rgx[256];
    __shared__ int   rsl[256];
    const int tid = threadIdx.x;

    for (int i = tid; i < 4096; i += 256) { cv[i] = candv[i]; ci[i] = candi[i]; }
    __syncthreads();

    for (int r = 0; r < KTOP; ++r) {
        float bv = -1e38f; int bg = 0x7fffffff; int bs = tid * 16;
        #pragma unroll
        for (int i = 0; i < 16; ++i) {
            int s = tid * 16 + i;
            float v = cv[s]; int g = ci[s];
            if (v > bv || (v == bv && g < bg)) { bv = v; bg = g; bs = s; }
        }
        rv[tid] = bv; rgx[tid] = bg; rsl[tid] = bs;
        __syncthreads();
        for (int off = 128; off > 0; off >>= 1) {
            if (tid < off) {
                if (rv[tid + off] > rv[tid] ||
                    (rv[tid + off] == rv[tid] && rgx[tid + off] < rgx[tid])) {
                    rv[tid] = rv[tid + off]; rgx[tid] = rgx[tid + off]; rsl[tid] = rsl[tid + off];
                }
            }
            __syncthreads();
        }
        if (tid == 0) {
            topi_ws[r] = rgx[0]; cv[rsl[0]] = -1e30f;
        }
        __syncthreads();
    }
}

// ---------------- Stage 2c: EXACT fp32 rescore partials (16 blocks) ----------
// Block b owns d-slice [b*64, (b+1)*64): hp[b][r][n] = sum_d x[topi[r]][d]*Wa1[d][n]
__global__ __launch_bounds__(256) void k_rescore(
    const float* __restrict__ x, const float* __restrict__ Wa1,
    const int* __restrict__ topi_ws, float* __restrict__ hp)
{
    __shared__ float sx[KTOP][64];
    __shared__ int   sti[KTOP];
    const int b = blockIdx.x, tid = threadIdx.x;
    if (tid < KTOP) sti[tid] = topi_ws[tid];
    __syncthreads();
    for (int i = tid; i < KTOP * 64; i += 256) {
        int r = i >> 6, d = i & 63;
        sx[r][d] = x[(size_t)sti[r] * D_IN + b * 64 + d];
    }
    __syncthreads();

    const int n = tid & 127, h = tid >> 7;   // h: row-half (8 rows each)
    float ac[8];
    #pragma unroll
    for (int rr = 0; rr < 8; ++rr) ac[rr] = 0.f;
    #pragma unroll 4
    for (int d = 0; d < 64; ++d) {
        const float w = Wa1[(size_t)(b * 64 + d) * A_DIM + n];
        #pragma unroll
        for (int rr = 0; rr < 8; ++rr)
            ac[rr] = fmaf(sx[h * 8 + rr][d], w, ac[rr]);
    }
    #pragma unroll
    for (int rr = 0; rr < 8; ++rr)
        hp[((size_t)b * KTOP + h * 8 + rr) * 128 + n] = ac[rr];
}

// ---------------- Stage 2d: finish rescore, sort, softmax, scatter, embed ----
__global__ __launch_bounds__(256) void k_final2(
    const float* __restrict__ hp, const float* __restrict__ ba1,
    const float* __restrict__ Wa2, const float* __restrict__ ba2,
    const float* __restrict__ x, const int* __restrict__ topi_ws,
    float* __restrict__ out, float* __restrict__ emb)
{
    __shared__ float sred[KTOP][128];
    __shared__ int   topi[KTOP];
    __shared__ float exv[KTOP];
    __shared__ float attn[KTOP];
    __shared__ int   order[KTOP];
    const int tid = threadIdx.x;
    if (tid < KTOP) topi[tid] = topi_ws[tid];

    // sum the 16 d-slice partials; tanh; weight by Wa2
    {
        const int n = tid & 127, h = tid >> 7;
        const float bn = ba1[n], wn = Wa2[n];
        #pragma unroll
        for (int rr = 0; rr < 8; ++rr) {
            const int r = h * 8 + rr;
            float s = 0.f;
            #pragma unroll
            for (int b = 0; b < 16; ++b)
                s += hp[((size_t)b * KTOP + r) * 128 + n];
            sred[r][n] = tanhf(s + bn) * wn;
        }
    }
    __syncthreads();
    if (tid < KTOP) {
        float s = ba2[0];
        for (int n = 0; n < 128; ++n) s += sred[tid][n];
        exv[tid] = s;
    }
    __syncthreads();

    // sort by (exact value desc, index asc) to match lax.top_k output order
    if (tid == 0) {
        #pragma unroll
        for (int k2 = 0; k2 < KTOP; ++k2) order[k2] = k2;
        for (int a2 = 1; a2 < KTOP; ++a2)
            for (int b2 = a2; b2 > 0; --b2) {
                int i1 = order[b2 - 1], i2 = order[b2];
                bool sw = (exv[i2] > exv[i1]) ||
                          (exv[i2] == exv[i1] && topi[i2] < topi[i1]);
                if (sw) { order[b2 - 1] = i2; order[b2] = i1; } else break;
            }
        float mx = exv[order[0]];
        float ssum = 0.f;
        for (int k2 = 0; k2 < KTOP; ++k2) {
            float e = expf(exv[order[k2]] - mx);
            attn[k2] = e; ssum += e;
        }
        float inv = 1.f / ssum;
        for (int k2 = 0; k2 < KTOP; ++k2) attn[k2] *= inv;
    }
    __syncthreads();

    if (tid < KTOP) {
        int src = order[tid];
        out[OUT_TOPI + tid] = (float)topi[src];
        out[OUT_FW + topi[src]] = attn[tid];
    }

    // ---- embedding: 4 dims per thread, coalesced float4 gathers -------------
    float4 e = {0.f, 0.f, 0.f, 0.f};
    #pragma unroll
    for (int k2 = 0; k2 < KTOP; ++k2) {
        const int src = order[k2];
        const float a = attn[k2];
        const float4 xv = *(const float4*)(x + (size_t)topi[src] * D_IN + tid * 4);
        e.x = fmaf(a, xv.x, e.x);
        e.y = fmaf(a, xv.y, e.y);
        e.z = fmaf(a, xv.z, e.z);
        e.w = fmaf(a, xv.w, e.w);
    }
    out[OUT_EMB + tid * 4 + 0] = e.x;   // OUT_EMB offset is odd -> scalar stores
    out[OUT_EMB + tid * 4 + 1] = e.y;
    out[OUT_EMB + tid * 4 + 2] = e.z;
    out[OUT_EMB + tid * 4 + 3] = e.w;
    *(float4*)(emb + tid * 4) = e;
}

// ---------------- Stage 4a: h partial sums (16 blocks over d-slices) ---------
__global__ __launch_bounds__(256) void k_mlp1(
    const float* __restrict__ emb, const float* __restrict__ Wc1,
    float* __restrict__ hpart)
{
    __shared__ float se[64];
    const int b = blockIdx.x, tid = threadIdx.x;
    if (tid < 64) se[tid] = emb[b * 64 + tid];
    __syncthreads();
    float p = 0.f;
    #pragma unroll 8
    for (int d = 0; d < 64; ++d)
        p = fmaf(se[d], Wc1[(size_t)(b * 64 + d) * H_DIM + tid], p);
    hpart[b * H_DIM + tid] = p;
}

// ---------------- Stage 4b: relu + Wc2 dot + bias ----------------------------
__global__ __launch_bounds__(256) void k_logit(
    const float* __restrict__ hpart, const float* __restrict__ bc1,
    const float* __restrict__ Wc2, const float* __restrict__ bc2,
    float* __restrict__ out)
{
    __shared__ float red[256];
    const int tid = threadIdx.x;
    float h = bc1[tid];
    #pragma unroll
    for (int i = 0; i < 16; ++i) h += hpart[i * H_DIM + tid];
    h = fmaxf(h, 0.f) * Wc2[tid];
    red[tid] = h;
    __syncthreads();
    for (int off = 128; off > 0; off >>= 1) {
        if (tid < off) red[tid] += red[tid + off];
        __syncthreads();
    }
    if (tid == 0) out[OUT_LOGIT] = red[0] + bc2[0];
}

// ---------------- Launch ------------------------------------------------------
extern "C" void kernel_launch(void* const* d_in, const int* in_sizes, int n_in,
                              void* d_out, int out_size, void* d_ws, size_t ws_size,
                              hipStream_t stream)
{
    const float* x   = (const float*)d_in[0];
    const float* Wa1 = (const float*)d_in[1];
    const float* ba1 = (const float*)d_in[2];
    const float* Wa2 = (const float*)d_in[3];
    const float* ba2 = (const float*)d_in[4];
    const float* Wc1 = (const float*)d_in[5];
    const float* bc1 = (const float*)d_in[6];
    const float* Wc2 = (const float*)d_in[7];
    const float* bc2 = (const float*)d_in[8];
    float* out = (float*)d_out;
    float* ws  = (float*)d_ws;

    float* scores = ws + WS_SCORES;
    float* candv  = ws + WS_CANDV;
    int*   candi  = (int*)(ws + WS_CANDI);
    int*   topi   = (int*)(ws + WS_TOPI);
    float* emb    = ws + WS_EMB;
    float* hpart  = ws + WS_HPART;
    float* hp2    = ws + WS_HP2;
    uint4* wpk    = (uint4*)(ws + WS_WPK);

    dim3 blk(256);
    k_prepack<<<64, blk, 0, stream>>>(Wa1, wpk);
    k_scores<<<(N_PATCH + 127) / 128, blk, 0, stream>>>(x, wpk, ba1, Wa2, ba2, scores);
    k_topk_local<<<NB2A, blk, 0, stream>>>(scores, candv, candi, out + OUT_FW);
    k_select<<<1, blk, 0, stream>>>(candv, candi, topi);
    k_rescore<<<16, blk, 0, stream>>>(x, Wa1, topi, hp2);
    k_final2<<<1, blk, 0, stream>>>(hp2, ba1, Wa2, ba2, x, topi, out, emb);
    k_mlp1<<<16, blk, 0, stream>>>(emb, Wc1, hpart);
    k_logit<<<1, blk, 0, stream>>>(hpart, bc1, Wc2, bc2, out);
}